// Round 16
// baseline (201.238 us; speedup 1.0000x reference)
//
#include <hip/hip_runtime.h>
#include <stdint.h>

typedef unsigned short u16;
typedef __bf16 bf16x8 __attribute__((ext_vector_type(8)));
typedef __bf16 bf16x2 __attribute__((ext_vector_type(2)));
typedef float f32x4 __attribute__((ext_vector_type(4)));
typedef float f32x16 __attribute__((ext_vector_type(16)));

#define SEQ    2048
#define NHEAD  16
#define DH     64
#define DMODEL 1024
#define NBH    64     // B*H

__device__ __forceinline__ u16 cvt1(float f){
  union { __bf16 h; u16 u; } c; c.h = (__bf16)f; return c.u;
}
__device__ __forceinline__ uint32_t cvt2(float a, float b){
  union { bf16x2 v; uint32_t u; } c; c.v = bf16x2{(__bf16)a, (__bf16)b}; return c.u;
}
__device__ __forceinline__ int swz(int row){ return (((row&7)^((row>>3)&7))<<4); }

#if __has_builtin(__builtin_amdgcn_exp2f)
__device__ __forceinline__ float EXP2(float x){ return __builtin_amdgcn_exp2f(x); }
#else
__device__ __forceinline__ float EXP2(float x){ return exp2f(x); }
#endif
__device__ __forceinline__ float max3f(float a, float b, float c){
  float r; asm("v_max3_f32 %0, %1, %2, %3" : "=v"(r) : "v"(a), "v"(b), "v"(c));
  return r;
}

typedef const __attribute__((address_space(1))) uint32_t* gas_t;
typedef __attribute__((address_space(3))) uint32_t* las_t;
__device__ __forceinline__ void async16(const void* g, void* l){
  __builtin_amdgcn_global_load_lds((gas_t)g, (las_t)l, 16, 0, 0);
}

// pack V rows (kv0, kv0+1) into sigma-permuted transposed LDS tile via v_perm
__device__ __forceinline__ void vstore8(char* dst, uint2 a0, uint2 a1,
                                        uint2 b0, uint2 b1, int dc, int vpos){
  uint32_t pk[8];
  pk[0] = __builtin_amdgcn_perm(b0.x, a0.x, 0x05040100u);
  pk[1] = __builtin_amdgcn_perm(b0.x, a0.x, 0x07060302u);
  pk[2] = __builtin_amdgcn_perm(b0.y, a0.y, 0x05040100u);
  pk[3] = __builtin_amdgcn_perm(b0.y, a0.y, 0x07060302u);
  pk[4] = __builtin_amdgcn_perm(b1.x, a1.x, 0x05040100u);
  pk[5] = __builtin_amdgcn_perm(b1.x, a1.x, 0x07060302u);
  pk[6] = __builtin_amdgcn_perm(b1.y, a1.y, 0x05040100u);
  pk[7] = __builtin_amdgcn_perm(b1.y, a1.y, 0x07060302u);
#pragma unroll
  for (int e=0;e<8;e++){
    const int row = dc*8 + e;
    *(uint32_t*)(dst + ((row*128 + vpos*2) ^ swz(row))) = pk[e];
  }
}

// ---------------- fused prep: 5x f32->bf16 convert + RoPE table -------------
__global__ void prep(const float* __restrict__ x,  const float* __restrict__ Wq,
                     const float* __restrict__ Wk, const float* __restrict__ Wv,
                     const float* __restrict__ Wo,
                     u16* __restrict__ xb, u16* __restrict__ wqkv,
                     u16* __restrict__ wob, float* __restrict__ tab)
{
  const int bid = blockIdx.x, tid = threadIdx.x;
  if (bid < 6144){
    const float* src; u16* dst; int lb;
    if      (bid < 4096){ src = x;  dst = xb;              lb = bid; }
    else if (bid < 4608){ src = Wq; dst = wqkv;            lb = bid-4096; }
    else if (bid < 5120){ src = Wk; dst = wqkv + 1048576;  lb = bid-4608; }
    else if (bid < 5632){ src = Wv; dst = wqkv + 2097152;  lb = bid-5120; }
    else                { src = Wo; dst = wob;             lb = bid-5632; }
    const size_t off = (size_t)lb*2048 + tid*8;
    float4 a = *(const float4*)(src+off);
    float4 b = *(const float4*)(src+off+4);
    bf16x8 o = { (__bf16)a.x,(__bf16)a.y,(__bf16)a.z,(__bf16)a.w,
                 (__bf16)b.x,(__bf16)b.y,(__bf16)b.z,(__bf16)b.w };
    *(bf16x8*)(dst+off) = o;
  } else {
    const int t = (bid-6144)*256 + tid;          // < 65536
    const int s = t >> 5, j = t & 31;
    double freq = exp(-(double)(2*j)/64.0*log(10000.0));
    double ang = (double)s*freq;
    tab[s*64 + 2*j]     = (float)cos(ang);
    tab[s*64 + 2*j + 1] = (float)sin(ang);
  }
}

// ---------------- QKV GEMM: 256^2 tile, 8 waves, 4-phase/K-tile schedule ----
// Staging FIXED to lane-linear LDS dest (m104: gload_lds writes base+lane*16;
// R14's per-lane *32 dest scrambled -> NaN). Swizzle lives entirely on the
// global source column; read-side inverse unchanged. One counted vmcnt(2)
// per K-tile (FIFO: oldest 8 = tile t's loads). B frags persist in regs.
__global__ __launch_bounds__(512, 1)
void gemm256(const u16* __restrict__ A, const u16* __restrict__ W,
             const float* __restrict__ b0, const float* __restrict__ b1,
             const float* __restrict__ b2,
             u16* __restrict__ dq, u16* __restrict__ dk, u16* __restrict__ dv,
             const float* __restrict__ tab)
{
  __shared__ u16 Ab[2][256*64];   // 32KB per buffer
  __shared__ u16 Bb[2][256*64];
  const int tid = threadIdx.x, lane = tid & 63;
  const int w8 = tid >> 6, wm = w8 >> 2, wn = w8 & 3;
  const int c0 = lane & 15, g = lane >> 4;
  const int id = blockIdx.x;                 // 384 blocks
  const int by = (id & 7)*4 + ((id >> 3) & 3);
  const int bx = id >> 5;
  const int m0 = by * 256, n0 = bx * 256;

  f32x4 acc[8][4] = {};

  // staging (lane-linear): thread tid covers LDS bytes tid*16 (+8192 for k=1)
  // -> rows srow = tid>>3 and srow+64, chunk tid&7; global col pre-swizzled.
  const int srow = tid >> 3;                 // 0..63
  const int gcol = (((tid & 7) ^ (srow & 7)) << 4);

#define STG(p, kt, nb) do{ \
    const char* _s = ((p) < 2 \
      ? (const char*)A + (size_t)(m0 + ((p)&1)*128 + srow)*2048 \
      : (const char*)W + (size_t)(n0 + ((p)&1)*128 + srow)*2048) + (kt)*128 + gcol; \
    char* _d = (((p) < 2) ? (char*)Ab[nb] : (char*)Bb[nb]) + ((p)&1)*16384 + tid*16; \
    async16(_s,           _d); \
    async16(_s + 64*2048, _d + 8192); \
  }while(0)

  STG(0,0,0); STG(1,0,0); STG(2,0,0); STG(3,0,0);

  bf16x8 bfr[2][4];
#pragma unroll 1
  for (int t = 0; t < 16; ++t){
    const int ct = t & 1, nb = ct ^ 1;
    // ---- phase 0: all B + A-quarter 0 ----
    if (t < 15){
      STG(0, t+1, nb);
      asm volatile("s_waitcnt vmcnt(2)" ::: "memory");
    } else {
      asm volatile("s_waitcnt vmcnt(0)" ::: "memory");
    }
    __builtin_amdgcn_s_barrier();
    __builtin_amdgcn_sched_barrier(0);
    {
#pragma unroll
      for (int kk=0;kk<2;kk++)
#pragma unroll
        for (int j=0;j<4;j++){
          const int rb = wn*64 + j*16 + c0;
          bfr[kk][j] = *(const bf16x8*)((const char*)Bb[ct] + rb*128 + ((((kk*4+g) ^ (rb&7)))<<4));
        }
      bf16x8 af[2][2];
#pragma unroll
      for (int kk=0;kk<2;kk++)
#pragma unroll
        for (int ii=0;ii<2;ii++){
          const int ra = wm*128 + ii*16 + c0;
          af[kk][ii] = *(const bf16x8*)((const char*)Ab[ct] + ra*128 + ((((kk*4+g) ^ (ra&7)))<<4));
        }
      asm volatile("s_waitcnt lgkmcnt(0)" ::: "memory");
      __builtin_amdgcn_sched_barrier(0);
      __builtin_amdgcn_s_setprio(1);
#pragma unroll
      for (int kk=0;kk<2;kk++)
#pragma unroll
        for (int ii=0;ii<2;ii++)
#pragma unroll
          for (int j=0;j<4;j++)
            acc[ii][j] = __builtin_amdgcn_mfma_f32_16x16x32_bf16(af[kk][ii], bfr[kk][j], acc[ii][j], 0,0,0);
      __builtin_amdgcn_s_setprio(0);
    }
    __builtin_amdgcn_s_barrier();
    __builtin_amdgcn_sched_barrier(0);
    // ---- phases 1..3: A-quarters 1..3, B from regs ----
#pragma unroll
    for (int p=1;p<4;p++){
      if (t < 15) STG(p, t+1, nb);
      __builtin_amdgcn_s_barrier();
      __builtin_amdgcn_sched_barrier(0);
      bf16x8 af[2][2];
#pragma unroll
      for (int kk=0;kk<2;kk++)
#pragma unroll
        for (int ii=0;ii<2;ii++){
          const int ra = wm*128 + (2*p+ii)*16 + c0;
          af[kk][ii] = *(const bf16x8*)((const char*)Ab[ct] + ra*128 + ((((kk*4+g) ^ (ra&7)))<<4));
        }
      asm volatile("s_waitcnt lgkmcnt(0)" ::: "memory");
      __builtin_amdgcn_sched_barrier(0);
      __builtin_amdgcn_s_setprio(1);
#pragma unroll
      for (int kk=0;kk<2;kk++)
#pragma unroll
        for (int ii=0;ii<2;ii++)
#pragma unroll
          for (int j=0;j<4;j++)
            acc[2*p+ii][j] = __builtin_amdgcn_mfma_f32_16x16x32_bf16(af[kk][ii], bfr[kk][j], acc[2*p+ii][j], 0,0,0);
      __builtin_amdgcn_s_setprio(0);
      __builtin_amdgcn_s_barrier();
      __builtin_amdgcn_sched_barrier(0);
    }
  }
#undef STG

  // ---- epilogue: bias + RoPE (q,k) + per-head scatter ----
  const int nbase = n0 + wn*64;
  const int tsel = n0 >> 10;                // 0=q 1=k 2=v
  const float* bias = (tsel==0) ? b0 : (tsel==1) ? b1 : b2;
  float bv4[4];
#pragma unroll
  for (int j=0;j<4;j++) bv4[j] = bias[(nbase & 1023) + j*16 + c0];
  u16* dst = (tsel==0) ? dq : (tsel==1) ? dk : dv;
  const float qs = (tsel==0) ? 0.18033688011f : 1.0f;   // 0.125*log2(e)
  const int h = (nbase >> 6) & (NHEAD-1);
#pragma unroll
  for (int i=0;i<8;i++){
    const int mbase = m0 + wm*128 + i*16 + g*4;
#pragma unroll
    for (int r=0;r<4;r++){
      const int mm = mbase + r;
      const int bb = mm >> 11, s = mm & (SEQ-1);
      const size_t rowbase = (((size_t)(bb*NHEAD + h))*SEQ + s)*DH;
      if (tsel < 2){
#pragma unroll
        for (int j2=0;j2<2;j2++){
          const int dh = j2*16 + c0;
          const float xl = acc[i][j2][r]   + bv4[j2];
          const float xh = acc[i][j2+2][r] + bv4[j2+2];
          const float2 cs = *(const float2*)(tab + (size_t)s*64 + dh*2);
          dst[rowbase + dh]      = cvt1((xl*cs.x - xh*cs.y)*qs);
          dst[rowbase + dh + 32] = cvt1((xh*cs.x + xl*cs.y)*qs);
        }
      } else {
#pragma unroll
        for (int j=0;j<4;j++)
          dst[rowbase + j*16 + c0] = cvt1(acc[i][j][r] + bv4[j]);
      }
    }
  }
}

// ---------------- O-proj GEMM: R12 structure (best measured) ----------------
__global__ __launch_bounds__(256, 2)
void gemm_o(const u16* __restrict__ A, const u16* __restrict__ W,
            const float* __restrict__ b0, float* __restrict__ fout)
{
  __shared__ u16 Ab[2][128*64];
  __shared__ u16 Bb[2][128*64];
  const int tid = threadIdx.x;
  const int lane = tid & 63;
  const int w = tid >> 6, wr = w >> 1, wc = w & 1;
  const int id = blockIdx.x;
  const int bx = id >> 6;
  const int by = ((id & 7) << 3) | ((id >> 3) & 7);
  const int m0 = by * 128;
  const int n0 = bx * 128;
  const int c0 = lane & 15, g = lane >> 4;

  f32x4 acc[4][4] = {};

  const int srow = tid >> 3;
  const int gcol = (((tid & 7) ^ (srow & 7)) << 4);
  const char* ga = (const char*)A + (size_t)(m0 + srow)*2048 + gcol;
  const char* gb = (const char*)W + (size_t)(n0 + srow)*2048 + gcol;
  const int ldst = tid*16;

#define STAGE_O(buf, kbyte) do{ \
    _Pragma("unroll") \
    for (int k=0;k<4;k++){ \
      async16(ga + (kbyte) + k*32*2048, (char*)Ab[buf] + k*4096 + ldst); \
      async16(gb + (kbyte) + k*32*2048, (char*)Bb[buf] + k*4096 + ldst); \
    } \
  }while(0)

#define COMPUTE_O(buf) do{ \
    bf16x8 afr[2][4], bfr[2][4]; \
    _Pragma("unroll") \
    for (int kk=0;kk<2;kk++){ \
      _Pragma("unroll") \
      for (int i=0;i<4;i++){ \
        const int ra = wr*64 + i*16 + c0; \
        afr[kk][i] = *(const bf16x8*)((const char*)Ab[buf] + ra*128 + ((((kk*4+g) ^ (ra&7))) << 4)); \
        const int rb = wc*64 + i*16 + c0; \
        bfr[kk][i] = *(const bf16x8*)((const char*)Bb[buf] + rb*128 + ((((kk*4+g) ^ (rb&7))) << 4)); \
      } \
    } \
    __builtin_amdgcn_s_setprio(1); \
    _Pragma("unroll") \
    for (int kk=0;kk<2;kk++) \
      _Pragma("unroll") \
      for (int i=0;i<4;i++) \
        _Pragma("unroll") \
        for (int j=0;j<4;j++) \
          acc[i][j] = __builtin_amdgcn_mfma_f32_16x16x32_bf16(afr[kk][i], bfr[kk][j], acc[i][j], 0,0,0); \
    __builtin_amdgcn_s_setprio(0); \
  }while(0)

  STAGE_O(0, 0);
#pragma unroll 1
  for (int it = 0; it < 15; ++it) {
    const int cur = it & 1;
    STAGE_O(cur ^ 1, (it+1)*128);
    asm volatile("s_waitcnt vmcnt(8)" ::: "memory");
    __builtin_amdgcn_s_barrier();
    __builtin_amdgcn_sched_barrier(0);
    COMPUTE_O(cur);
    __builtin_amdgcn_s_barrier();
    __builtin_amdgcn_sched_barrier(0);
  }
  asm volatile("s_waitcnt vmcnt(0)" ::: "memory");
  __builtin_amdgcn_s_barrier();
  __builtin_amdgcn_sched_barrier(0);
  COMPUTE_O(1);
#undef STAGE_O
#undef COMPUTE_O

  const int nbase = n0 + wc*64;
  float bv4[4];
#pragma unroll
  for (int j=0;j<4;j++) bv4[j] = b0[(nbase & 1023) + j*16 + c0];
#pragma unroll
  for (int i=0;i<4;i++){
    const int mbase = m0 + wr*64 + i*16 + g*4;
#pragma unroll
    for (int j=0;j<4;j++){
#pragma unroll
      for (int r=0;r<4;r++)
        fout[(size_t)(mbase + r) * DMODEL + nbase + j*16 + c0] = acc[i][j][r] + bv4[j];
    }
  }
}

// ---------------- Flash attention: 4 waves x 32q (QB=128), 32x32x16 ---------
// grid (64, 8): x = bh (XCD: id%8 = bh%8), y = pair; qt = pair / 15-pair
__global__ __launch_bounds__(256, 2)
void attn_fwd(const u16* __restrict__ Q, const u16* __restrict__ K,
              const u16* __restrict__ V, u16* __restrict__ O)
{
  __shared__ u16 Kb[2][64*64];  // [kv][dh], swizzled (pre-swizzled source)
  __shared__ u16 Vt[2][64*64];  // [dh][pos], swizzled; pos = sigma^-1(kv)
  const int bh = blockIdx.x;
  const int pair = blockIdx.y;              // 0..7
  const int tid = threadIdx.x, lane = tid & 63, w = tid >> 6;  // w in [0,4)
  const int c31 = lane & 31, hi = lane >> 5;
  const size_t hb = (size_t)bh * SEQ * DH;
  const int b = bh >> 4, h = bh & 15;

  const int boff1 = tid*16;
  const int ksw1  = boff1 ^ swz(boff1 >> 7);
  const int boff2 = boff1 + 4096;
  const int ksw2  = boff2 ^ swz(boff2 >> 7);
  const int rp = tid >> 3, dc = tid & 7;
  const int kv0 = 2*rp;
  const int vpos = (kv0 & 0x33) | ((kv0 & 4) << 1) | ((kv0 & 8) >> 1);

#pragma unroll 1
  for (int half = 0; half < 2; half++){
    const int qt = half ? (15 - pair) : pair;
    const int qrow_base = qt*128 + w*32;
    const int jt_last  = 2*qt + 1;
    const int jt_end_w = 2*qt + (w>>1);     // this wave's diagonal tile
    const int q = qrow_base + c31;          // this lane's q-row

    bf16x8 qf[4];
#pragma unroll
    for (int kc=0;kc<4;kc++)
      qf[kc] = *(const bf16x8*)(Q + hb + (size_t)q*DH + kc*16 + hi*8);

    f32x16 oacc0 = {}, oacc1 = {};          // O^T[dh][q]
    float mrun = -3.0e38f, lrun = 0.f;

    {
      const char* gk = (const char*)(K + hb);
      async16(gk + ksw1, (char*)Kb[0] + boff1);
      async16(gk + ksw2, (char*)Kb[0] + boff2);
      const u16* gv = V + hb;
      uint2 a0 = *(const uint2*)(gv + (kv0  )*DH + dc*8);
      uint2 a1 = *(const uint2*)(gv + (kv0  )*DH + dc*8 + 4);
      uint2 b0 = *(const uint2*)(gv + (kv0+1)*DH + dc*8);
      uint2 b1 = *(const uint2*)(gv + (kv0+1)*DH + dc*8 + 4);
      vstore8((char*)Vt[0], a0, a1, b0, b1, dc, vpos);
    }
    __syncthreads();

    uint2 pa0, pa1, pb0, pb1;
    for (int jt = 0; jt <= jt_last; jt++){
      const int cur = jt & 1, nxt = cur ^ 1;
      const bool pre = (jt < jt_last);
      if (pre){
        const char* gk = (const char*)(K + hb + (size_t)(jt+1)*64*DH);
        async16(gk + ksw1, (char*)Kb[nxt] + boff1);
        async16(gk + ksw2, (char*)Kb[nxt] + boff2);
        const u16* gv = V + hb + (size_t)(jt+1)*64*DH;
        pa0 = *(const uint2*)(gv + (kv0  )*DH + dc*8);
        pa1 = *(const uint2*)(gv + (kv0  )*DH + dc*8 + 4);
        pb0 = *(const uint2*)(gv + (kv0+1)*DH + dc*8);
        pb1 = *(const uint2*)(gv + (kv0+1)*DH + dc*8 + 4);
      }

      if (jt <= jt_end_w){
        f32x16 sT[2] = {};
#pragma unroll
        for (int kc=0;kc<4;kc++){
          const int col = (kc*16 + hi*8)*2;
          const int r0 = c31, r1 = 32 + c31;
          const bf16x8 kf0 = *(const bf16x8*)((const char*)Kb[cur] + ((r0*128 + col) ^ swz(r0)));
          const bf16x8 kf1 = *(const bf16x8*)((const char*)Kb[cur] + ((r1*128 + col) ^ swz(r1)));
          __builtin_amdgcn_s_setprio(1);
          sT[0] = __builtin_amdgcn_mfma_f32_32x32x16_bf16(kf0, qf[kc], sT[0], 0,0,0);
          sT[1] = __builtin_amdgcn_mfma_f32_32x32x16_bf16(kf1, qf[kc], sT[1], 0,0,0);
          __builtin_amdgcn_s_setprio(0);
        }
        if (jt == jt_end_w){
#pragma unroll
          for (int kvb=0;kvb<2;kvb++)
#pragma unroll
            for (int r=0;r<16;r++){
              const int kv = jt*64 + kvb*32 + (r&3) + 8*(r>>2) + 4*hi;
              sT[kvb][r] = (kv <= q) ? sT[kvb][r] : -3.0e38f;
            }
        }
        float mx0 = -3.0e38f, mx1 = -3.0e38f;
#pragma unroll
        for (int r=0;r<16;r+=2){
          mx0 = max3f(mx0, sT[0][r], sT[0][r+1]);
          mx1 = max3f(mx1, sT[1][r], sT[1][r+1]);
        }
        float mx = fmaxf(mx0, mx1);
        mx = fmaxf(mx, __shfl_xor(mx, 32));
        const bool grow = __any(mx > mrun + 8.0f);
        float corr = 1.0f;
        if (grow){
          const float mnew = fmaxf(mrun, mx);
          corr = EXP2(mrun - mnew);
          mrun = mnew;
        }
        float ls[4] = {0.f, 0.f, 0.f, 0.f};
#pragma unroll
        for (int kvb=0;kvb<2;kvb++)
#pragma unroll
          for (int r=0;r<16;r++){
            const float p = EXP2(sT[kvb][r] - mrun);
            sT[kvb][r] = p;
            ls[r & 3] += p;
          }
        float lsum = (ls[0] + ls[1]) + (ls[2] + ls[3]);
        lsum += __shfl_xor(lsum, 32);
        lrun = lrun*corr + lsum;
        if (grow){
#pragma unroll
          for (int r=0;r<16;r++){ oacc0[r] *= corr; oacc1[r] *= corr; }
        }
#pragma unroll
        for (int kvb=0;kvb<2;kvb++)
#pragma unroll
          for (int s=0;s<2;s++){
            union { bf16x8 v; uint32_t d[4]; } pa;
#pragma unroll
            for (int j=0;j<4;j++)
              pa.d[j] = cvt2(sT[kvb][s*8+2*j], sT[kvb][s*8+2*j+1]);
            const int col = (kvb*32 + s*16 + hi*8)*2;
            const int r0 = c31, r1 = 32 + c31;
            const bf16x8 vf0 = *(const bf16x8*)((const char*)Vt[cur] + ((r0*128 + col) ^ swz(r0)));
            const bf16x8 vf1 = *(const bf16x8*)((const char*)Vt[cur] + ((r1*128 + col) ^ swz(r1)));
            __builtin_amdgcn_s_setprio(1);
            oacc0 = __builtin_amdgcn_mfma_f32_32x32x16_bf16(vf0, pa.v, oacc0, 0,0,0);
            oacc1 = __builtin_amdgcn_mfma_f32_32x32x16_bf16(vf1, pa.v, oacc1, 0,0,0);
            __builtin_amdgcn_s_setprio(0);
          }
      }

      if (pre) vstore8((char*)Vt[nxt], pa0, pa1, pb0, pb1, dc, vpos);
      __syncthreads();
    }

    {
      const float inv = 1.0f / lrun;
      u16* orow = O + ((size_t)b*SEQ + q)*DMODEL + h*DH;
#pragma unroll
      for (int r2=0;r2<8;r2++){
        const int dh0 = 2*(r2&1) + 8*(r2>>1) + 4*hi;
        *(uint32_t*)(orow + dh0)      = cvt2(oacc0[2*r2]*inv, oacc0[2*r2+1]*inv);
        *(uint32_t*)(orow + 32 + dh0) = cvt2(oacc1[2*r2]*inv, oacc1[2*r2+1]*inv);
      }
    }
  }
}

// ---------------------------------------------------------------------------
extern "C" void kernel_launch(void* const* d_in, const int* in_sizes, int n_in,
                              void* d_out, int out_size, void* d_ws, size_t ws_size,
                              hipStream_t stream)
{
  const float* x  = (const float*)d_in[0];
  const float* Wq = (const float*)d_in[1];
  const float* bq = (const float*)d_in[2];
  const float* Wk = (const float*)d_in[3];
  const float* bk = (const float*)d_in[4];
  const float* Wv = (const float*)d_in[5];
  const float* bv = (const float*)d_in[6];
  const float* Wo = (const float*)d_in[7];
  const float* bo = (const float*)d_in[8];
  // d_in[9]: causal mask (int32) — implemented analytically, not read.

  const size_t MB = 1024*1024;
  char* ws = (char*)d_ws;
  u16*  xb   = (u16*)(ws);                 // [0,16MB)  x bf16; dead after QKV
  u16*  aw   = (u16*)(ws);                 // attn out reuses region
  u16*  vw   = (u16*)(ws + 16*MB);         // [16,32MB) V [B,H,S,Dh]
  u16*  wqkv = (u16*)(ws + 32*MB);         // [32,38MB) Wq|Wk|Wv bf16 [3072][1024]
  u16*  wob  = (u16*)(ws + 38*MB);         // [38,40MB)
  float* tab = (float*)(ws + 41*MB);       // 512KB
  // d_out (32MB f32) doubles as scratch for q/k (bf16, dead before final GEMM)
  u16*  qw = (u16*)d_out;
  u16*  kw = (u16*)d_out + 8*MB;

  prep<<<dim3(6400), dim3(256), 0, stream>>>(x, Wq, Wk, Wv, Wo, xb, wqkv, wob, tab);

  // fused QKV projection + RoPE epilogue: 256^2 tiles, 384 blocks
  gemm256<<<dim3(384), dim3(512), 0, stream>>>(xb, wqkv, bq, bk, bv,
                                               qw, kw, vw, tab);

  attn_fwd<<<dim3(64, 8), dim3(256), 0, stream>>>(qw, kw, vw, aw);

  gemm_o<<<dim3(512), dim3(256), 0, stream>>>(aw, wob, bo, (float*)d_out);
}

// Round 17
// 162.832 us; speedup vs baseline: 1.2359x; 1.2359x over previous
//
#include <hip/hip_runtime.h>
#include <stdint.h>

typedef unsigned short u16;
typedef __bf16 bf16x8 __attribute__((ext_vector_type(8)));
typedef __bf16 bf16x2 __attribute__((ext_vector_type(2)));
typedef float f32x4 __attribute__((ext_vector_type(4)));
typedef float f32x16 __attribute__((ext_vector_type(16)));

#define SEQ    2048
#define NHEAD  16
#define DH     64
#define DMODEL 1024
#define NBH    64     // B*H

__device__ __forceinline__ u16 cvt1(float f){
  union { __bf16 h; u16 u; } c; c.h = (__bf16)f; return c.u;
}
__device__ __forceinline__ uint32_t cvt2(float a, float b){
  union { bf16x2 v; uint32_t u; } c; c.v = bf16x2{(__bf16)a, (__bf16)b}; return c.u;
}
__device__ __forceinline__ int swz(int row){ return (((row&7)^((row>>3)&7))<<4); }

#if __has_builtin(__builtin_amdgcn_exp2f)
__device__ __forceinline__ float EXP2(float x){ return __builtin_amdgcn_exp2f(x); }
#else
__device__ __forceinline__ float EXP2(float x){ return exp2f(x); }
#endif
__device__ __forceinline__ float max3f(float a, float b, float c){
  float r; asm("v_max3_f32 %0, %1, %2, %3" : "=v"(r) : "v"(a), "v"(b), "v"(c));
  return r;
}

typedef const __attribute__((address_space(1))) uint32_t* gas_t;
typedef __attribute__((address_space(3))) uint32_t* las_t;
__device__ __forceinline__ void async16(const void* g, void* l){
  __builtin_amdgcn_global_load_lds((gas_t)g, (las_t)l, 16, 0, 0);
}

// pack V rows (kv0, kv0+1) into sigma-permuted transposed LDS tile via v_perm
__device__ __forceinline__ void vstore8(char* dst, uint2 a0, uint2 a1,
                                        uint2 b0, uint2 b1, int dc, int vpos){
  uint32_t pk[8];
  pk[0] = __builtin_amdgcn_perm(b0.x, a0.x, 0x05040100u);
  pk[1] = __builtin_amdgcn_perm(b0.x, a0.x, 0x07060302u);
  pk[2] = __builtin_amdgcn_perm(b0.y, a0.y, 0x05040100u);
  pk[3] = __builtin_amdgcn_perm(b0.y, a0.y, 0x07060302u);
  pk[4] = __builtin_amdgcn_perm(b1.x, a1.x, 0x05040100u);
  pk[5] = __builtin_amdgcn_perm(b1.x, a1.x, 0x07060302u);
  pk[6] = __builtin_amdgcn_perm(b1.y, a1.y, 0x05040100u);
  pk[7] = __builtin_amdgcn_perm(b1.y, a1.y, 0x07060302u);
#pragma unroll
  for (int e=0;e<8;e++){
    const int row = dc*8 + e;
    *(uint32_t*)(dst + ((row*128 + vpos*2) ^ swz(row))) = pk[e];
  }
}

// ---------------- fused prep: 5x f32->bf16 convert + RoPE table -------------
__global__ void prep(const float* __restrict__ x,  const float* __restrict__ Wq,
                     const float* __restrict__ Wk, const float* __restrict__ Wv,
                     const float* __restrict__ Wo,
                     u16* __restrict__ xb, u16* __restrict__ wqkv,
                     u16* __restrict__ wob, float* __restrict__ tab)
{
  const int bid = blockIdx.x, tid = threadIdx.x;
  if (bid < 6144){
    const float* src; u16* dst; int lb;
    if      (bid < 4096){ src = x;  dst = xb;              lb = bid; }
    else if (bid < 4608){ src = Wq; dst = wqkv;            lb = bid-4096; }
    else if (bid < 5120){ src = Wk; dst = wqkv + 1048576;  lb = bid-4608; }
    else if (bid < 5632){ src = Wv; dst = wqkv + 2097152;  lb = bid-5120; }
    else                { src = Wo; dst = wob;             lb = bid-5632; }
    const size_t off = (size_t)lb*2048 + tid*8;
    float4 a = *(const float4*)(src+off);
    float4 b = *(const float4*)(src+off+4);
    bf16x8 o = { (__bf16)a.x,(__bf16)a.y,(__bf16)a.z,(__bf16)a.w,
                 (__bf16)b.x,(__bf16)b.y,(__bf16)b.z,(__bf16)b.w };
    *(bf16x8*)(dst+off) = o;
  } else {
    const int t = (bid-6144)*256 + tid;          // < 65536
    const int s = t >> 5, j = t & 31;
    double freq = exp(-(double)(2*j)/64.0*log(10000.0));
    double ang = (double)s*freq;
    tab[s*64 + 2*j]     = (float)cos(ang);
    tab[s*64 + 2*j + 1] = (float)sin(ang);
  }
}

// ---------------- GEMM: dst = A @ W^T + bias  (bf16 in, NT layout) ----------
// R12-best config (162.9us total): BK=64 dbuf, counted vmcnt(8), conflict-free
// 3-bit XOR swizzle (0 conflicts), XCD-sliced 1D block remap (L2-resident A).
template<int MODE>
__global__ __launch_bounds__(256, 2)
void gemm_bt(const u16* __restrict__ A, const u16* __restrict__ W,
             const float* __restrict__ b0, const float* __restrict__ b1,
             const float* __restrict__ b2, float* __restrict__ fout,
             u16* __restrict__ dq, u16* __restrict__ dk, u16* __restrict__ dv,
             const float* __restrict__ tab)
{
  __shared__ u16 Ab[2][128*64];   // 16KB per buffer
  __shared__ u16 Bb[2][128*64];
  const int tid = threadIdx.x;
  const int lane = tid & 63;
  const int w = tid >> 6, wr = w >> 1, wc = w & 1;
  const int id = blockIdx.x;
  const int bx = id >> 6;                              // N tile
  const int by = ((id & 7) << 3) | ((id >> 3) & 7);    // M tile (XCD-sliced)
  const int m0 = by * 128;
  const int n0 = bx * 128;
  const int c0 = lane & 15, g = lane >> 4;

  f32x4 acc[4][4] = {};

  const int srow = tid >> 3;
  const int gcol = (((tid & 7) ^ (srow & 7)) << 4);
  const char* ga = (const char*)A + (size_t)(m0 + srow)*2048 + gcol;
  const char* gb = (const char*)W + (size_t)(n0 + srow)*2048 + gcol;
  const int ldst = tid*16;

#define STAGE_G(buf, kbyte) do{ \
    _Pragma("unroll") \
    for (int k=0;k<4;k++){ \
      async16(ga + (kbyte) + k*32*2048, (char*)Ab[buf] + k*4096 + ldst); \
      async16(gb + (kbyte) + k*32*2048, (char*)Bb[buf] + k*4096 + ldst); \
    } \
  }while(0)

#define COMPUTE_G(buf) do{ \
    bf16x8 afr[2][4], bfr[2][4]; \
    _Pragma("unroll") \
    for (int kk=0;kk<2;kk++){ \
      _Pragma("unroll") \
      for (int i=0;i<4;i++){ \
        const int ra = wr*64 + i*16 + c0; \
        afr[kk][i] = *(const bf16x8*)((const char*)Ab[buf] + ra*128 + ((((kk*4+g) ^ (ra&7))) << 4)); \
        const int rb = wc*64 + i*16 + c0; \
        bfr[kk][i] = *(const bf16x8*)((const char*)Bb[buf] + rb*128 + ((((kk*4+g) ^ (rb&7))) << 4)); \
      } \
    } \
    __builtin_amdgcn_s_setprio(1); \
    _Pragma("unroll") \
    for (int kk=0;kk<2;kk++) \
      _Pragma("unroll") \
      for (int i=0;i<4;i++) \
        _Pragma("unroll") \
        for (int j=0;j<4;j++) \
          acc[i][j] = __builtin_amdgcn_mfma_f32_16x16x32_bf16(afr[kk][i], bfr[kk][j], acc[i][j], 0,0,0); \
    __builtin_amdgcn_s_setprio(0); \
  }while(0)

  STAGE_G(0, 0);
#pragma unroll 1
  for (int it = 0; it < 15; ++it) {
    const int cur = it & 1;
    STAGE_G(cur ^ 1, (it+1)*128);
    asm volatile("s_waitcnt vmcnt(8)" ::: "memory");
    __builtin_amdgcn_s_barrier();
    __builtin_amdgcn_sched_barrier(0);
    COMPUTE_G(cur);
    __builtin_amdgcn_s_barrier();
    __builtin_amdgcn_sched_barrier(0);
  }
  asm volatile("s_waitcnt vmcnt(0)" ::: "memory");
  __builtin_amdgcn_s_barrier();
  __builtin_amdgcn_sched_barrier(0);
  COMPUTE_G(1);
#undef STAGE_G
#undef COMPUTE_G

  const int nbase = n0 + wc*64;
  const int t = n0 >> 10;                 // 0=q 1=k 2=v (tiles never cross)
  const float* bias = (MODE==1) ? b0 : (t==0) ? b0 : (t==1) ? b1 : b2;
  float bv4[4];
#pragma unroll
  for (int j=0;j<4;j++) bv4[j] = bias[(nbase & 1023) + j*16 + c0];

  if (MODE == 0) {
    u16* dst = (t==0) ? dq : (t==1) ? dk : dv;
    const float qs = (t==0) ? 0.18033688011f : 1.0f;   // 0.125*log2(e)
    const int h = (nbase >> 6) & (NHEAD-1);
#pragma unroll
    for (int i=0;i<4;i++){
      const int mbase = m0 + wr*64 + i*16 + g*4;
#pragma unroll
      for (int r=0;r<4;r++){
        const int mm = mbase + r;
        const int bb = mm >> 11, s = mm & (SEQ-1);
        const size_t rowbase = (((size_t)(bb*NHEAD + h))*SEQ + s)*DH;
        if (t < 2) {
#pragma unroll
          for (int j2=0;j2<2;j2++){
            const int dh = j2*16 + c0;
            const float xl = acc[i][j2][r]   + bv4[j2];
            const float xh = acc[i][j2+2][r] + bv4[j2+2];
            const float2 cs = *(const float2*)(tab + (size_t)s*64 + dh*2);
            dst[rowbase + dh]      = cvt1((xl*cs.x - xh*cs.y)*qs);
            dst[rowbase + dh + 32] = cvt1((xh*cs.x + xl*cs.y)*qs);
          }
        } else {
#pragma unroll
          for (int j=0;j<4;j++)
            dst[rowbase + j*16 + c0] = cvt1(acc[i][j][r] + bv4[j]);
        }
      }
    }
  } else {
#pragma unroll
    for (int i=0;i<4;i++){
      const int mbase = m0 + wr*64 + i*16 + g*4;
#pragma unroll
      for (int j=0;j<4;j++){
#pragma unroll
        for (int r=0;r<4;r++)
          fout[(size_t)(mbase + r) * DMODEL + nbase + j*16 + c0] = acc[i][j][r] + bv4[j];
      }
    }
  }
}

// ---------------- Flash attention: 4 waves x 32q, counted-vmcnt pipeline ----
// grid (64, 8): x = bh (XCD: id%8 = bh%8), y = pair; qt = pair / 15-pair.
// T4: raw s_barrier + counted waits; next tile's 2 K-asyncs stay in flight
// ACROSS the barrier (old __syncthreads drained vmcnt(0) every iteration).
// Issue order per iter: 4 V reg-loads -> sched_barrier -> 2 K async16;
// compute waits vmcnt(6) (retire cur tile's K, FIFO-oldest); vstore8 waits
// vmcnt(2) (retire V, keep K in flight); lgkmcnt(0)+s_barrier (LDS vis only).
__global__ __launch_bounds__(256, 2)
void attn_fwd(const u16* __restrict__ Q, const u16* __restrict__ K,
              const u16* __restrict__ V, u16* __restrict__ O)
{
  __shared__ u16 Kb[2][64*64];  // [kv][dh], swizzled (pre-swizzled source)
  __shared__ u16 Vt[2][64*64];  // [dh][pos], swizzled; pos = sigma^-1(kv)
  const int bh = blockIdx.x;
  const int pair = blockIdx.y;              // 0..7
  const int tid = threadIdx.x, lane = tid & 63, w = tid >> 6;  // w in [0,4)
  const int c31 = lane & 31, hi = lane >> 5;
  const size_t hb = (size_t)bh * SEQ * DH;
  const int b = bh >> 4, h = bh & 15;

  const int boff1 = tid*16;
  const int ksw1  = boff1 ^ swz(boff1 >> 7);
  const int boff2 = boff1 + 4096;
  const int ksw2  = boff2 ^ swz(boff2 >> 7);
  const int rp = tid >> 3, dc = tid & 7;
  const int kv0 = 2*rp;
  const int vpos = (kv0 & 0x33) | ((kv0 & 4) << 1) | ((kv0 & 8) >> 1);

#pragma unroll 1
  for (int half = 0; half < 2; half++){
    const int qt = half ? (15 - pair) : pair;
    const int qrow_base = qt*128 + w*32;
    const int jt_last  = 2*qt + 1;
    const int jt_end_w = 2*qt + (w>>1);     // this wave's diagonal tile
    const int q = qrow_base + c31;          // this lane's q-row

    bf16x8 qf[4];
#pragma unroll
    for (int kc=0;kc<4;kc++)
      qf[kc] = *(const bf16x8*)(Q + hb + (size_t)q*DH + kc*16 + hi*8);

    f32x16 oacc0 = {}, oacc1 = {};          // O^T[dh][q]
    float mrun = -3.0e38f, lrun = 0.f;

    uint2 pa0, pa1, pb0, pb1;               // V prefetch regs

    // ---- prologue: stage tile 0 (full drain via __syncthreads is fine:
    //      iter 0's vmcnt(6) then waits on nothing, data already resident) --
    {
      const u16* gv = V + hb;
      pa0 = *(const uint2*)(gv + (kv0  )*DH + dc*8);
      pa1 = *(const uint2*)(gv + (kv0  )*DH + dc*8 + 4);
      pb0 = *(const uint2*)(gv + (kv0+1)*DH + dc*8);
      pb1 = *(const uint2*)(gv + (kv0+1)*DH + dc*8 + 4);
      __builtin_amdgcn_sched_barrier(0);
      const char* gk = (const char*)(K + hb);
      async16(gk + ksw1, (char*)Kb[0] + boff1);
      async16(gk + ksw2, (char*)Kb[0] + boff2);
      vstore8((char*)Vt[0], pa0, pa1, pb0, pb1, dc, vpos);
    }
    __syncthreads();

    for (int jt = 0; jt <= jt_last; jt++){
      const int cur = jt & 1, nxt = cur ^ 1;
      const bool pre = (jt < jt_last);
      if (pre){
        const u16* gv = V + hb + (size_t)(jt+1)*64*DH;
        pa0 = *(const uint2*)(gv + (kv0  )*DH + dc*8);
        pa1 = *(const uint2*)(gv + (kv0  )*DH + dc*8 + 4);
        pb0 = *(const uint2*)(gv + (kv0+1)*DH + dc*8);
        pb1 = *(const uint2*)(gv + (kv0+1)*DH + dc*8 + 4);
        __builtin_amdgcn_sched_barrier(0);   // pin: V loads BEFORE K asyncs
        const char* gk = (const char*)(K + hb + (size_t)(jt+1)*64*DH);
        async16(gk + ksw1, (char*)Kb[nxt] + boff1);
        async16(gk + ksw2, (char*)Kb[nxt] + boff2);
      }

      if (jt <= jt_end_w){
        // retire cur tile's 2 K-asyncs (FIFO-oldest); keep this iter's 6 live
        if (pre) asm volatile("s_waitcnt vmcnt(6)" ::: "memory");
        else     asm volatile("s_waitcnt vmcnt(0)" ::: "memory");
        // ---- S^T = K Q'^T : sT[kvb][r] = S[kv][q], kv=(r&3)+8(r>>2)+4hi ----
        f32x16 sT[2] = {};
#pragma unroll
        for (int kc=0;kc<4;kc++){
          const int col = (kc*16 + hi*8)*2;
          const int r0 = c31, r1 = 32 + c31;
          const bf16x8 kf0 = *(const bf16x8*)((const char*)Kb[cur] + ((r0*128 + col) ^ swz(r0)));
          const bf16x8 kf1 = *(const bf16x8*)((const char*)Kb[cur] + ((r1*128 + col) ^ swz(r1)));
          __builtin_amdgcn_s_setprio(1);
          sT[0] = __builtin_amdgcn_mfma_f32_32x32x16_bf16(kf0, qf[kc], sT[0], 0,0,0);
          sT[1] = __builtin_amdgcn_mfma_f32_32x32x16_bf16(kf1, qf[kc], sT[1], 0,0,0);
          __builtin_amdgcn_s_setprio(0);
        }
        // ---- causal mask: only this wave's diagonal tile ----
        if (jt == jt_end_w){
#pragma unroll
          for (int kvb=0;kvb<2;kvb++)
#pragma unroll
            for (int r=0;r<16;r++){
              const int kv = jt*64 + kvb*32 + (r&3) + 8*(r>>2) + 4*hi;
              sT[kvb][r] = (kv <= q) ? sT[kvb][r] : -3.0e38f;
            }
        }
        // ---- online softmax (exp2 domain; defer-max; parallel chains) ----
        float mx0 = -3.0e38f, mx1 = -3.0e38f;
#pragma unroll
        for (int r=0;r<16;r+=2){
          mx0 = max3f(mx0, sT[0][r], sT[0][r+1]);
          mx1 = max3f(mx1, sT[1][r], sT[1][r+1]);
        }
        float mx = fmaxf(mx0, mx1);
        mx = fmaxf(mx, __shfl_xor(mx, 32));
        const bool grow = __any(mx > mrun + 8.0f);
        float corr = 1.0f;
        if (grow){
          const float mnew = fmaxf(mrun, mx);
          corr = EXP2(mrun - mnew);
          mrun = mnew;
        }
        float ls[4] = {0.f, 0.f, 0.f, 0.f};
#pragma unroll
        for (int kvb=0;kvb<2;kvb++)
#pragma unroll
          for (int r=0;r<16;r++){
            const float p = EXP2(sT[kvb][r] - mrun);
            sT[kvb][r] = p;
            ls[r & 3] += p;
          }
        float lsum = (ls[0] + ls[1]) + (ls[2] + ls[3]);
        lsum += __shfl_xor(lsum, 32);
        lrun = lrun*corr + lsum;
        if (grow){
#pragma unroll
          for (int r=0;r<16;r++){ oacc0[r] *= corr; oacc1[r] *= corr; }
        }
        // ---- O^T += V^T P^T (P in-register; V sigma-permuted in LDS) ----
#pragma unroll
        for (int kvb=0;kvb<2;kvb++)
#pragma unroll
          for (int s=0;s<2;s++){
            union { bf16x8 v; uint32_t d[4]; } pa;
#pragma unroll
            for (int j=0;j<4;j++)
              pa.d[j] = cvt2(sT[kvb][s*8+2*j], sT[kvb][s*8+2*j+1]);
            const int col = (kvb*32 + s*16 + hi*8)*2;
            const int r0 = c31, r1 = 32 + c31;
            const bf16x8 vf0 = *(const bf16x8*)((const char*)Vt[cur] + ((r0*128 + col) ^ swz(r0)));
            const bf16x8 vf1 = *(const bf16x8*)((const char*)Vt[cur] + ((r1*128 + col) ^ swz(r1)));
            __builtin_amdgcn_s_setprio(1);
            oacc0 = __builtin_amdgcn_mfma_f32_32x32x16_bf16(vf0, pa.v, oacc0, 0,0,0);
            oacc1 = __builtin_amdgcn_mfma_f32_32x32x16_bf16(vf1, pa.v, oacc1, 0,0,0);
            __builtin_amdgcn_s_setprio(0);
          }
      }

      if (pre){
        // retire the 4 V loads; leave nxt tile's 2 K-asyncs in flight
        asm volatile("s_waitcnt vmcnt(2)" ::: "memory");
        vstore8((char*)Vt[nxt], pa0, pa1, pb0, pb1, dc, vpos);
      }
      // LDS-write visibility only — no VMEM drain across this barrier
      asm volatile("s_waitcnt lgkmcnt(0)" ::: "memory");
      __builtin_amdgcn_s_barrier();
      __builtin_amdgcn_sched_barrier(0);
    }

    // ---- write attn output (per-lane q-col): O[b, q, h*64 + dh] ----
    {
      const float inv = 1.0f / lrun;
      u16* orow = O + ((size_t)b*SEQ + q)*DMODEL + h*DH;
#pragma unroll
      for (int r2=0;r2<8;r2++){
        const int dh0 = 2*(r2&1) + 8*(r2>>1) + 4*hi;
        *(uint32_t*)(orow + dh0)      = cvt2(oacc0[2*r2]*inv, oacc0[2*r2+1]*inv);
        *(uint32_t*)(orow + 32 + dh0) = cvt2(oacc1[2*r2]*inv, oacc1[2*r2+1]*inv);
      }
    }
  }
}

// ---------------------------------------------------------------------------
extern "C" void kernel_launch(void* const* d_in, const int* in_sizes, int n_in,
                              void* d_out, int out_size, void* d_ws, size_t ws_size,
                              hipStream_t stream)
{
  const float* x  = (const float*)d_in[0];
  const float* Wq = (const float*)d_in[1];
  const float* bq = (const float*)d_in[2];
  const float* Wk = (const float*)d_in[3];
  const float* bk = (const float*)d_in[4];
  const float* Wv = (const float*)d_in[5];
  const float* bv = (const float*)d_in[6];
  const float* Wo = (const float*)d_in[7];
  const float* bo = (const float*)d_in[8];
  // d_in[9]: causal mask (int32) — implemented analytically, not read.

  const size_t MB = 1024*1024;
  char* ws = (char*)d_ws;
  u16*  xb   = (u16*)(ws);                 // [0,16MB)  x bf16; dead after QKV
  u16*  aw   = (u16*)(ws);                 // attn out reuses region
  u16*  vw   = (u16*)(ws + 16*MB);         // [16,32MB) V [B,H,S,Dh]
  u16*  wqkv = (u16*)(ws + 32*MB);         // [32,38MB) Wq|Wk|Wv bf16 [3072][1024]
  u16*  wob  = (u16*)(ws + 38*MB);         // [38,40MB)
  float* tab = (float*)(ws + 41*MB);       // 512KB
  // d_out (32MB f32) doubles as scratch for q/k (bf16, dead before final GEMM)
  u16*  qw = (u16*)d_out;
  u16*  kw = (u16*)d_out + 8*MB;

  prep<<<dim3(6400), dim3(256), 0, stream>>>(x, Wq, Wk, Wv, Wo, xb, wqkv, wob, tab);

  // fused QKV projection + RoPE epilogue: N=3072 (1D grid, XCD-remapped)
  gemm_bt<0><<<dim3(1536), dim3(256), 0, stream>>>(xb, wqkv, bq, bk, bv,
                                                   nullptr, qw, kw, vw, tab);

  attn_fwd<<<dim3(64, 8), dim3(256), 0, stream>>>(qw, kw, vw, aw);

  gemm_bt<1><<<dim3(512), dim3(256), 0, stream>>>(aw, wob, bo, nullptr, nullptr,
                                                  (float*)d_out, nullptr, nullptr, nullptr, nullptr);
}